// Round 2
// baseline (375.533 us; speedup 1.0000x reference)
//
#include <hip/hip_runtime.h>
#include <math.h>
#include <cstddef>

#define EPS 1e-5f

typedef __attribute__((ext_vector_type(8))) short bf16x8;
typedef __attribute__((ext_vector_type(4))) float f32x4;

__device__ __forceinline__ float wave_sum(float v) {
#pragma unroll
  for (int o = 32; o > 0; o >>= 1) v += __shfl_xor(v, o, 64);
  return v;
}

// fp32 -> bf16 bits, round-to-nearest-even (finite inputs only)
__device__ __forceinline__ unsigned short f2b(float f) {
  union { float f; unsigned int u; } v; v.f = f;
  unsigned int r = (v.u + 0x7FFFu + ((v.u >> 16) & 1u)) >> 16;
  return (unsigned short)r;
}
__device__ __forceinline__ float b2f(unsigned short u) {
  union { unsigned int u; float f; } v; v.u = ((unsigned int)u) << 16;
  return v.f;
}

// packed f32x2 -> bf16x2 (RNE), gfx950 HW instruction
__device__ __forceinline__ unsigned int pk2(float lo, float hi) {
  unsigned int r;
  asm volatile("v_cvt_pk_bf16_f32 %0, %1, %2" : "=v"(r) : "v"(lo), "v"(hi));
  return r;
}

__device__ __forceinline__ bf16x8 pack8(const float* o) {
  union { unsigned int u[4]; bf16x8 v; } r;
  r.u[0] = pk2(o[0], o[1]); r.u[1] = pk2(o[2], o[3]);
  r.u[2] = pk2(o[4], o[5]); r.u[3] = pk2(o[6], o[7]);
  return r.v;
}

// ============ Weight pre-conversion: fp32 -> bf16, 8 arrays in one launch ==
struct WConvArgs {
  const float* src[8];
  unsigned short* dst[8];
  int n[8];
};
__global__ __launch_bounds__(256) void conv_w(WConvArgs a) {
  const int arr = blockIdx.y;
  const int i = (blockIdx.x * 256 + threadIdx.x) * 4;
  if (i >= a.n[arr]) return;
  const float4 f = *(const float4*)(a.src[arr] + i);
  unsigned short t[4] = {f2b(f.x), f2b(f.y), f2b(f.z), f2b(f.w)};
  unsigned short* d = a.dst[arr] + i;
  *(ushort2*)d = *(ushort2*)&t[0];
  *(ushort2*)(d + 2) = *(ushort2*)&t[2];
}

// ============ MFMA GEMM v2: C[2048,N] = A[2048,KK] @ W[N,KK]^T + bias ======
// A staged whole-K in LDS by a fused prologue; K-loop double-buffers W only.
// PRO: 0 = A bf16 copy, 1 = A f32 convert, 2 = inorm(A f32) rows,
//      3 = LN(A f32; lnw,lnb) rows, 4 = LN then feat0n+inorm (final merge),
//      5 = attention 4-split merge (po partials + pm denominators).
// WRB: blockIdx.y==0 writes the normalized rows (f32) to wrb for later
//      residual use. RESID: epilogue adds Rf. SCALEQ: cols<512 scaled 1/8.
template <int RELU, int PRO, int OUT_F32, int OUT_BF16, int RESID, int SCALEQ,
          int WRB, int KK>
__global__ __launch_bounds__(256) void gemm2(
    const void* __restrict__ Aptr, const float* __restrict__ pmp,
    const float* __restrict__ lnw, const float* __restrict__ lnb,
    const float* __restrict__ add0, float* __restrict__ wrb,
    const unsigned short* __restrict__ W, const float* __restrict__ bias,
    const float* __restrict__ Rf, float* __restrict__ Cf,
    unsigned short* __restrict__ Cb, int N) {
  __shared__ __align__(16) unsigned short As[32][KK + 8];
  __shared__ __align__(16) unsigned short Ws[2][64][72];
  const int tid = threadIdx.x;
  const int wid = tid >> 6, lane = tid & 63;
  const int ln = lane & 15, quad = lane >> 4;
  const int m0 = blockIdx.x * 32, n0 = blockIdx.y * 64;

  // ---- prologue: build As[32][KK] ----
  if (PRO == 0) {
    const int row = tid >> 3, seg = tid & 7;
    const unsigned short* ap =
        (const unsigned short*)Aptr + (size_t)(m0 + row) * KK + seg * 8;
#pragma unroll
    for (int j = 0; j < KK / 64; ++j)
      *(bf16x8*)&As[row][seg * 8 + j * 64] = *(const bf16x8*)(ap + j * 64);
  } else if (PRO == 1) {
    const int row = tid >> 3, seg = tid & 7;
    const float* ap = (const float*)Aptr + (size_t)(m0 + row) * KK + seg * 8;
#pragma unroll
    for (int j = 0; j < KK / 64; ++j) {
      float4 a = *(const float4*)(ap + j * 64);
      float4 b = *(const float4*)(ap + j * 64 + 4);
      float o[8] = {a.x, a.y, a.z, a.w, b.x, b.y, b.z, b.w};
      *(bf16x8*)&As[row][seg * 8 + j * 64] = pack8(o);
    }
  } else if (PRO == 5) {
    const int row = tid >> 3, seg = tid & 7;
    const unsigned short* pob = (const unsigned short*)Aptr;
#pragma unroll
    for (int j = 0; j < 8; ++j) {  // head j == 64-col group j
      float l = pmp[(size_t)j * 2048 + m0 + row] +
                pmp[(size_t)(8 + j) * 2048 + m0 + row] +
                pmp[(size_t)(16 + j) * 2048 + m0 + row] +
                pmp[(size_t)(24 + j) * 2048 + m0 + row];
      float inv = 1.f / l;
      float o[8] = {0.f, 0.f, 0.f, 0.f, 0.f, 0.f, 0.f, 0.f};
#pragma unroll
      for (int s = 0; s < 4; ++s) {
        bf16x8 v = *(const bf16x8*)(
            pob + ((size_t)((s * 8 + j) * 2048 + m0 + row)) * 64 + seg * 8);
#pragma unroll
        for (int k = 0; k < 8; ++k) o[k] += b2f((unsigned short)v[k]);
      }
#pragma unroll
      for (int k = 0; k < 8; ++k) o[k] *= inv;
      *(bf16x8*)&As[row][j * 64 + seg * 8] = pack8(o);
    }
  } else {  // PRO 2/3/4: row-wise normalize over 512 f32 (KK == 512)
    float wv[8], bv[8];
    if (PRO == 3 || PRO == 4) {
      float4 w0 = *(const float4*)(lnw + lane * 8);
      float4 w1 = *(const float4*)(lnw + lane * 8 + 4);
      float4 b0 = *(const float4*)(lnb + lane * 8);
      float4 b1 = *(const float4*)(lnb + lane * 8 + 4);
      wv[0] = w0.x; wv[1] = w0.y; wv[2] = w0.z; wv[3] = w0.w;
      wv[4] = w1.x; wv[5] = w1.y; wv[6] = w1.z; wv[7] = w1.w;
      bv[0] = b0.x; bv[1] = b0.y; bv[2] = b0.z; bv[3] = b0.w;
      bv[4] = b1.x; bv[5] = b1.y; bv[6] = b1.z; bv[7] = b1.w;
    }
#pragma unroll
    for (int rr = 0; rr < 8; ++rr) {
      const int row = wid * 8 + rr;
      const float* ap = (const float*)Aptr + (size_t)(m0 + row) * 512 + lane * 8;
      float4 a = *(const float4*)ap, b = *(const float4*)(ap + 4);
      float o[8] = {a.x, a.y, a.z, a.w, b.x, b.y, b.z, b.w};
      float s = 0.f, ss = 0.f;
#pragma unroll
      for (int k = 0; k < 8; ++k) s += o[k];
      float mean = wave_sum(s) * (1.f / 512.f);
#pragma unroll
      for (int k = 0; k < 8; ++k) { float d = o[k] - mean; ss += d * d; }
      float rs = rsqrtf(wave_sum(ss) * (1.f / 512.f) + EPS);
#pragma unroll
      for (int k = 0; k < 8; ++k) o[k] = (o[k] - mean) * rs;
      if (PRO == 3 || PRO == 4) {
#pragma unroll
        for (int k = 0; k < 8; ++k) o[k] = o[k] * wv[k] + bv[k];
      }
      if (PRO == 4) {  // v = feat0n + inorm(o)
        float s2 = 0.f, ss2 = 0.f;
#pragma unroll
        for (int k = 0; k < 8; ++k) s2 += o[k];
        float m2 = wave_sum(s2) * (1.f / 512.f);
#pragma unroll
        for (int k = 0; k < 8; ++k) { float d = o[k] - m2; ss2 += d * d; }
        float rs2 = rsqrtf(wave_sum(ss2) * (1.f / 512.f) + EPS);
        const float* zp = add0 + (size_t)(m0 + row) * 512 + lane * 8;
        float4 z0 = *(const float4*)zp, z1 = *(const float4*)(zp + 4);
        float z[8] = {z0.x, z0.y, z0.z, z0.w, z1.x, z1.y, z1.z, z1.w};
#pragma unroll
        for (int k = 0; k < 8; ++k) o[k] = z[k] + (o[k] - m2) * rs2;
      }
      if (WRB) {
        if (blockIdx.y == 0) {
          float* dp = wrb + (size_t)(m0 + row) * 512 + lane * 8;
          float4 o0 = {o[0], o[1], o[2], o[3]};
          float4 o1 = {o[4], o[5], o[6], o[7]};
          *(float4*)dp = o0;
          *(float4*)(dp + 4) = o1;
        }
      }
      *(bf16x8*)&As[row][lane * 8] = pack8(o);
    }
  }

  // ---- K-loop: W-only double-buffered staging ----
  const int wrow = tid >> 2, wseg = tid & 3;
  const int KS = KK / 64;
  bf16x8 rwb0, rwb1;
  auto load_w = [&](int ks) {
    const unsigned short* wp = W + (size_t)(n0 + wrow) * KK + ks * 64 + wseg * 16;
    rwb0 = *(const bf16x8*)wp;
    rwb1 = *(const bf16x8*)(wp + 8);
  };
  auto store_w = [&](int buf) {
    *(bf16x8*)&Ws[buf][wrow][wseg * 16] = rwb0;
    *(bf16x8*)&Ws[buf][wrow][wseg * 16 + 8] = rwb1;
  };

  f32x4 acc[2];
  acc[0] = (f32x4){0.f, 0.f, 0.f, 0.f};
  acc[1] = (f32x4){0.f, 0.f, 0.f, 0.f};
  const int mrow = (wid & 1) * 16, nh = wid >> 1;

  load_w(0);
  store_w(0);
  __syncthreads();  // covers As prologue + Ws[0]

#pragma unroll 1
  for (int ks = 0; ks < KS; ++ks) {
    const int cur = ks & 1;
    if (ks + 1 < KS) load_w(ks + 1);
#pragma unroll
    for (int kc = 0; kc < 2; ++kc) {
      bf16x8 af = *(const bf16x8*)&As[mrow + ln][ks * 64 + kc * 32 + quad * 8];
#pragma unroll
      for (int nt = 0; nt < 2; ++nt) {
        bf16x8 wf = *(const bf16x8*)&Ws[cur][nh * 32 + nt * 16 + ln][kc * 32 + quad * 8];
        acc[nt] = __builtin_amdgcn_mfma_f32_16x16x32_bf16(af, wf, acc[nt], 0, 0, 0);
      }
    }
    if (ks + 1 < KS) store_w(cur ^ 1);
    __syncthreads();
  }

  const int gm = m0 + mrow + quad * 4;
  const float qs = (SCALEQ && n0 < 512) ? 0.125f : 1.f;
#pragma unroll
  for (int nt = 0; nt < 2; ++nt) {
    const int gn = n0 + nh * 32 + nt * 16 + ln;
    float bvv = bias[gn];
#pragma unroll
    for (int r = 0; r < 4; ++r) {
      float v = acc[nt][r] + bvv;
      if (SCALEQ) v *= qs;
      if (RELU) v = fmaxf(v, 0.f);
      if (RESID) v += Rf[(size_t)(gm + r) * N + gn];
      if (OUT_F32) Cf[(size_t)(gm + r) * N + gn] = v;
      if (OUT_BF16) Cb[(size_t)(gm + r) * N + gn] = f2b(v);
    }
  }
}

// ============ Flash attention v8: swapped QK^T, packed in-register softmax =
__global__ __launch_bounds__(256) void flash_attn8(
    const unsigned short* __restrict__ qkv, float* __restrict__ pm,
    unsigned short* __restrict__ po) {
  __shared__ __align__(16) unsigned short Ks[64][72];
  __shared__ __align__(16) unsigned short Vt[64][72];
  __shared__ __align__(16) unsigned int Pp[64][36];  // packed P, stride 144B
  const int qt = blockIdx.x, h = blockIdx.y, sp = blockIdx.z;
  const int tid = threadIdx.x;
  const int wid = tid >> 6, lane = tid & 63;
  const int ln = lane & 15, quad = lane >> 4;
  const int wq0 = wid * 16;

  bf16x8 aq[2];
  {
    const unsigned short* qp =
        qkv + (size_t)(qt * 64 + wq0 + ln) * 1536 + h * 64 + quad * 8;
    aq[0] = *(const bf16x8*)qp;
    aq[1] = *(const bf16x8*)(qp + 32);
  }

  const int key = tid >> 2, seg = tid & 3;  // K staging
  bf16x8 rk0, rk1;
  unsigned short tv[16];

  auto load_kv = [&](int t) {
    const int g = sp * 8 + t;
    const unsigned short* kr =
        qkv + (size_t)(g * 64 + key) * 1536 + 512 + h * 64 + seg * 16;
    rk0 = *(const bf16x8*)kr;
    rk1 = *(const bf16x8*)(kr + 8);
#pragma unroll
    for (int j = 0; j < 16; ++j)
      tv[j] = qkv[(size_t)(g * 64 + wid * 16 + j) * 1536 + 1024 + h * 64 + lane];
  };
  auto store_kv = [&]() {
    *(bf16x8*)&Ks[key][seg * 16] = rk0;
    *(bf16x8*)&Ks[key][seg * 16 + 8] = rk1;
    *(bf16x8*)&Vt[lane][wid * 16] = *(const bf16x8*)&tv[0];
    *(bf16x8*)&Vt[lane][wid * 16 + 8] = *(const bf16x8*)&tv[8];
  };

  float l_r = 0.f;  // partial denom for q-row wq0+ln over this lane's keys
  f32x4 acc_o[4];
#pragma unroll
  for (int nt = 0; nt < 4; ++nt) acc_o[nt] = (f32x4){0.f, 0.f, 0.f, 0.f};

  load_kv(0);
  store_kv();
  __syncthreads();

#pragma unroll 1
  for (int t = 0; t < 8; ++t) {
    if (t + 1 < 8) load_kv(t + 1);  // global latency overlaps compute

    f32x4 s_acc[4];
#pragma unroll
    for (int nt = 0; nt < 4; ++nt) s_acc[nt] = (f32x4){0.f, 0.f, 0.f, 0.f};
#pragma unroll
    for (int nt = 0; nt < 4; ++nt) {
      bf16x8 kf0 = *(const bf16x8*)&Ks[nt * 16 + ln][quad * 8];
      bf16x8 kf1 = *(const bf16x8*)&Ks[nt * 16 + ln][32 + quad * 8];
      s_acc[nt] = __builtin_amdgcn_mfma_f32_16x16x32_bf16(kf0, aq[0], s_acc[nt], 0, 0, 0);
      s_acc[nt] = __builtin_amdgcn_mfma_f32_16x16x32_bf16(kf1, aq[1], s_acc[nt], 0, 0, 0);
    }

    // p = exp(s); pack pairs of consecutive keys; 4x ds_write_b64
#pragma unroll
    for (int nt = 0; nt < 4; ++nt) {
      float p0 = __expf(s_acc[nt][0]);
      float p1 = __expf(s_acc[nt][1]);
      float p2 = __expf(s_acc[nt][2]);
      float p3 = __expf(s_acc[nt][3]);
      l_r += (p0 + p1) + (p2 + p3);
      uint2 w;
      w.x = pk2(p0, p1);
      w.y = pk2(p2, p3);
      *(uint2*)&Pp[wq0 + ln][nt * 8 + quad * 2] = w;
    }

#pragma unroll
    for (int kc = 0; kc < 2; ++kc) {
      bf16x8 pf = *(const bf16x8*)&Pp[wq0 + ln][kc * 16 + quad * 4];
#pragma unroll
      for (int nt = 0; nt < 4; ++nt) {
        bf16x8 vf = *(const bf16x8*)&Vt[nt * 16 + ln][kc * 32 + quad * 8];
        acc_o[nt] = __builtin_amdgcn_mfma_f32_16x16x32_bf16(pf, vf, acc_o[nt], 0, 0, 0);
      }
    }
    __syncthreads();
    if (t + 1 < 8) {
      store_kv();
      __syncthreads();
    }
  }

  const size_t base = (size_t)((sp * 8 + h) * 2048 + qt * 64);
  float l = l_r;
  l += __shfl_xor(l, 16, 64);
  l += __shfl_xor(l, 32, 64);
  if (quad == 0) pm[base + wq0 + ln] = l;
#pragma unroll
  for (int r = 0; r < 4; ++r) {
    const size_t row = base + wq0 + quad * 4 + r;
#pragma unroll
    for (int nt = 0; nt < 4; ++nt)
      po[row * 64 + nt * 16 + ln] = f2b(acc_o[nt][r]);
  }
}

// dist with fused inorm128: one wave per row
__global__ __launch_bounds__(256) void dist2(const float* __restrict__ fq,
                                             const float* __restrict__ hi,
                                             const float* __restrict__ ne,
                                             float* __restrict__ out) {
  const int row = blockIdx.x * 4 + (threadIdx.x >> 6);
  const int lane = threadIdx.x & 63;
  float f0 = fq[(size_t)row * 128 + lane];
  float f1 = fq[(size_t)row * 128 + 64 + lane];
  float mean = wave_sum(f0 + f1) * (1.f / 128.f);
  float vs = (f0 - mean) * (f0 - mean) + (f1 - mean) * (f1 - mean);
  float rs = rsqrtf(wave_sum(vs) * (1.f / 128.f) + EPS);
  f0 = (f0 - mean) * rs;
  f1 = (f1 - mean) * rs;
  float mp = 1e30f, mn = 1e30f;
  for (int p = 0; p < 40; ++p) {
    float h0 = hi[p * 128 + lane], h1 = hi[p * 128 + 64 + lane];
    float d0 = f0 - h0, d1 = f1 - h1;
    float d2 = wave_sum(d0 * d0 + d1 * d1);
    mp = fminf(mp, d2);
    float n0 = ne[p * 128 + lane], n1 = ne[p * 128 + 64 + lane];
    d0 = f0 - n0; d1 = f1 - n1;
    d2 = wave_sum(d0 * d0 + d1 * d1);
    mn = fminf(mn, d2);
  }
  if (lane == 0) {
    out[row * 2 + 0] = -sqrtf(mn);
    out[row * 2 + 1] = -sqrtf(mp);
  }
}

extern "C" void kernel_launch(void* const* d_in, const int* in_sizes, int n_in,
                              void* d_out, int out_size, void* d_ws, size_t ws_size,
                              hipStream_t stream) {
  const float* x        = (const float*)d_in[0];
  const float* reduce_w = (const float*)d_in[1];
  const float* reduce_b = (const float*)d_in[2];
  const float* in_w     = (const float*)d_in[3];
  const float* in_b     = (const float*)d_in[4];
  const float* out_w    = (const float*)d_in[5];
  const float* out_b    = (const float*)d_in[6];
  const float* ff1_w    = (const float*)d_in[7];
  const float* ff1_b    = (const float*)d_in[8];
  const float* ff2_w    = (const float*)d_in[9];
  const float* ff2_b    = (const float*)d_in[10];
  const float* ln1_w    = (const float*)d_in[11];
  const float* ln1_b    = (const float*)d_in[12];
  const float* ln2_w    = (const float*)d_in[13];
  const float* ln2_b    = (const float*)d_in[14];
  const float* mlp_w1   = (const float*)d_in[15];
  const float* mlp_b1   = (const float*)d_in[16];
  const float* mlp_w2   = (const float*)d_in[17];
  const float* mlp_b2   = (const float*)d_in[18];
  const float* mlp_w3   = (const float*)d_in[19];
  const float* mlp_b3   = (const float*)d_in[20];
  const float* hi       = (const float*)d_in[21];
  const float* ne       = (const float*)d_in[22];
  float* out = (float*)d_out;
  float* ws = (float*)d_ws;

  const size_t MD = (size_t)2048 * 512;  // 1M elems
  float* feat0_f  = ws;                  // raw reduce output (f32)
  float* feat0n_f = ws + MD;             // inorm(feat0) (f32)
  float* feat_f   = ws + 2 * MD;         // rolling post-LN buffer (f32)
  float* tmp_f    = ws + 3 * MD;         // residual-summed pre-LN (f32)
  float* pm       = ws + 4 * MD;         // 4*8*2048 = 65536 f32
  unsigned short* u = (unsigned short*)(ws + 4 * MD + 65536);
  unsigned short* qkv_b   = u;            // 3*MD
  unsigned short* relu_b  = u + 3 * MD;   // MD
  unsigned short* po_b    = u + 4 * MD;   // 4*MD
  unsigned short* relu2_b = qkv_b;        // alias: attention done by then
  float* featq_f = tmp_f;                 // alias: tmp free after mlp1

  // bf16 weight region
  unsigned short* wb = u + 8 * MD;
  unsigned short* reduce_wb = wb;                   // 393216
  unsigned short* in_wb     = wb + 393216;          // 2359296
  unsigned short* out_wb    = in_wb + 2359296;      // 786432
  unsigned short* ff1_wb    = out_wb + 786432;      // 786432
  unsigned short* ff2_wb    = ff1_wb + 786432;      // 786432
  unsigned short* mlp_w1b   = ff2_wb + 786432;      // 262144
  unsigned short* mlp_w2b   = mlp_w1b + 262144;     // 262144
  unsigned short* mlp_w3b   = mlp_w2b + 262144;     // 65536

  dim3 blk(256);
  WConvArgs wa;
  wa.src[0] = reduce_w; wa.dst[0] = reduce_wb; wa.n[0] = 393216;
  wa.src[1] = in_w;     wa.dst[1] = in_wb;     wa.n[1] = 2359296;
  wa.src[2] = out_w;    wa.dst[2] = out_wb;    wa.n[2] = 786432;
  wa.src[3] = ff1_w;    wa.dst[3] = ff1_wb;    wa.n[3] = 786432;
  wa.src[4] = ff2_w;    wa.dst[4] = ff2_wb;    wa.n[4] = 786432;
  wa.src[5] = mlp_w1;   wa.dst[5] = mlp_w1b;   wa.n[5] = 262144;
  wa.src[6] = mlp_w2;   wa.dst[6] = mlp_w2b;   wa.n[6] = 262144;
  wa.src[7] = mlp_w3;   wa.dst[7] = mlp_w3b;   wa.n[7] = 65536;
  conv_w<<<dim3(2304, 8), blk, 0, stream>>>(wa);

  // reduce: feat0_f = x @ reduce_w^T + b   (raw; inorm fused into qkv0)
  gemm2<0, 1, 1, 0, 0, 0, 0, 768><<<dim3(64, 8), blk, 0, stream>>>(
      x, nullptr, nullptr, nullptr, nullptr, nullptr,
      reduce_wb, reduce_b, nullptr, feat0_f, nullptr, 512);

  for (int i = 0; i < 3; ++i) {
    if (i == 0) {
      // qkv0: prologue inorm(feat0 raw) -> writeback feat0n_f
      gemm2<0, 2, 0, 1, 0, 1, 1, 512><<<dim3(64, 24), blk, 0, stream>>>(
          feat0_f, nullptr, nullptr, nullptr, nullptr, feat0n_f,
          in_wb, in_b, nullptr, nullptr, qkv_b, 1536);
    } else {
      // qkv_i: prologue LN2(prev tmp) -> writeback feat_f
      gemm2<0, 3, 0, 1, 0, 1, 1, 512><<<dim3(64, 24), blk, 0, stream>>>(
          tmp_f, nullptr, ln2_w + (i - 1) * 512, ln2_b + (i - 1) * 512,
          nullptr, feat_f, in_wb + (size_t)i * 1536 * 512, in_b + i * 1536,
          nullptr, nullptr, qkv_b, 1536);
    }
    flash_attn8<<<dim3(32, 8, 4), blk, 0, stream>>>(qkv_b, pm, po_b);
    const float* fin_f = (i == 0) ? feat0n_f : feat_f;
    // merge: prologue 4-split merge; epilogue +residual -> tmp_f
    gemm2<0, 5, 1, 0, 1, 0, 0, 512><<<dim3(64, 8), blk, 0, stream>>>(
        po_b, pm, nullptr, nullptr, nullptr, nullptr,
        out_wb + (size_t)i * 512 * 512, out_b + i * 512,
        fin_f, tmp_f, nullptr, 512);
    // ff1: prologue LN1(tmp) -> writeback feat_f; relu out
    gemm2<1, 3, 0, 1, 0, 0, 1, 512><<<dim3(64, 8), blk, 0, stream>>>(
        tmp_f, nullptr, ln1_w + i * 512, ln1_b + i * 512, nullptr, feat_f,
        ff1_wb + (size_t)i * 512 * 512, ff1_b + i * 512,
        nullptr, nullptr, relu_b, 512);
    // ff2: +residual(feat_f) -> tmp_f
    gemm2<0, 0, 1, 0, 1, 0, 0, 512><<<dim3(64, 8), blk, 0, stream>>>(
        relu_b, nullptr, nullptr, nullptr, nullptr, nullptr,
        ff2_wb + (size_t)i * 512 * 512, ff2_b + i * 512,
        feat_f, tmp_f, nullptr, 512);
  }

  // mlp1: prologue LN2(tmp) then feat0n + inorm(.)
  gemm2<1, 4, 0, 1, 0, 0, 0, 512><<<dim3(64, 8), blk, 0, stream>>>(
      tmp_f, nullptr, ln2_w + 2 * 512, ln2_b + 2 * 512, feat0n_f, nullptr,
      mlp_w1b, mlp_b1, nullptr, nullptr, relu_b, 512);
  gemm2<1, 0, 0, 1, 0, 0, 0, 512><<<dim3(64, 8), blk, 0, stream>>>(
      relu_b, nullptr, nullptr, nullptr, nullptr, nullptr,
      mlp_w2b, mlp_b2, nullptr, nullptr, relu2_b, 512);
  gemm2<0, 0, 1, 0, 0, 0, 0, 512><<<dim3(64, 2), blk, 0, stream>>>(
      relu2_b, nullptr, nullptr, nullptr, nullptr, nullptr,
      mlp_w3b, mlp_b3, nullptr, featq_f, nullptr, 128);
  dist2<<<512, blk, 0, stream>>>(featq_f, hi, ne, out);
}